// Round 9
// baseline (254.788 us; speedup 1.0000x reference)
//
#include <hip/hip_runtime.h>

// RoiPooling via integral image — CHANNEL-GROUP PIPELINE, FAT-PACKED (round 9).
// G=2 groups of 256 channels, TWO slice sets (A,B) resident together in L3.
// Launches (stream order = dependency barrier; roles in one launch touch
// DISJOINT buffers, so no intra-kernel sync needed):
//   L1 scanK   : scan(g0 -> A)
//   L2 scanOffK: scan(g1 -> B)      || offset(A)      [offset rides free]
//   L3 gathOffK: gather(g0 from A)  || offset(B)      [no LDS -> full TLP]
//   L4 gathK   : gather(g1 from B)
// Round-8 result: slice reuse gave 270->246.6; all phases now < 80 us each.
// This round removes the two offset serialization points + 2 launch gaps.
// Row y=256 of S was dead (queries clamp ry<=255, offsetK reads rows <=248):
// dropped -> slice = 64.2+8.7 MB, 2 slices = 152.1 MB fits ws. All compute
// bodies byte-identical to round 8 -> output bit-identical.
//
// ws layout (floats):
//   S_A @ 0          8*256*257*32 = 16,842,752
//   OP_A@ 16842752   8*33*257*32  =  2,171,136
//   S_B @ 19013888   16,842,752
//   OP_B@ 35856640    2,171,136      end = 38,027,776 (152.1 MB)

#define CHN 512
#define WD  256
#define SP  257               // x-extent 0..256 (col 256 written, unread)
#define YS  256               // y-extent 0..255 (row 256 dead -> dropped)
#define YC  8                 // rows per y-chunk
#define NK  32                // number of y-chunks
#define CB  32                // channels per cb-block / innermost S dim
#define GCH 256               // channels per group

#define SIDX(cb, y, x)   ((((size_t)(cb) * YS + (y)) * SP + (x)) * CB)
#define OPIDX(cb, kk, x) ((((size_t)(cb) * 33 + (kk)) * SP + (x)) * CB)

#define S_SZ  ((size_t)8 * YS * SP * CB)   // 16,842,752 floats
#define OP_SZ ((size_t)8 * 33 * SP * CB)   //  2,171,136 floats

#define OFF_UNITS 129          // ceil(8*257*32 / 512) offset 512-thr units
#define GATH_UNITS 1024        // 4096 ROIs / 4 per 512-thr unit

typedef float f32x4v __attribute__((ext_vector_type(4)));

__device__ __forceinline__ float4 ntld4(const float* p) {   // streaming load
    f32x4v u = __builtin_nontemporal_load((const f32x4v*)p);
    return make_float4(u.x, u.y, u.z, u.w);
}

// Raw barrier: LDS-drain only, NO vmcnt(0) (keeps prefetch loads + S stores
// in flight across y-steps). lgkmcnt(0) drains this wave's ds_writes
// (producer visibility) and ds_reads (WAR safety for y+2 buffer reuse).
// Trailing empty asm stops LLVM hoisting post-barrier LDS reads.
#define BAR() do { asm volatile("s_waitcnt lgkmcnt(0)" ::: "memory"); \
                   __builtin_amdgcn_s_barrier(); \
                   asm volatile("" ::: "memory"); } while (0)

// ---------------- scan body: fm-group -> S-slice (chunk-local integral) ----
// One 512-thr block = tile 32c x 256x x 8y. bid in [0,256): cb=bid&7, k=bid>>3.
// LDS XOR swizzle col ^= 4*(row>>2): unswizzled store-phase reads were a
// deterministic 4-way bank conflict; swizzled: 0 (verified round 3).
__device__ __forceinline__ void scanBody(const float* __restrict__ fm,
                                         float* __restrict__ S,
                                         int bid, float tile[2][CB][260]) {
    const int t = threadIdx.x, lane = t & 63, w = t >> 6;   // w = wave 0..7
    const int cb = bid & 7;              // cb-block within group
    const int c0 = cb * CB;              // channel offset within group
    const int k  = bid >> 3;             // y-chunk 0..31
    const int y0 = k * YC;

    const int cg = t & 7;                // store: 4-channel group (8 groups = 32 ch)
    const int x8 = t >> 3;               // store: x mod 64
    const float4 z4 = make_float4(0.f, 0.f, 0.f, 0.f);

    if (k == 0) {                        // y=0 border row, x=0..255
        #pragma unroll
        for (int it = 0; it < 4; ++it) {
            const int lin = it * 512 + t;
            const int cgg = lin & 7, x = lin >> 3;
            *(float4*)(S + SIDX(cb, 0, x) + 4 * cgg) = z4;
        }
    }

    float4 cur[4], nxt[4];
    #pragma unroll
    for (int j = 0; j < 4; ++j)
        cur[j] = ntld4(fm + ((size_t)(c0 + w * 4 + j) << 16)
                          + (size_t)y0 * 256 + 4 * lane);

    float4 acc[4];
    #pragma unroll
    for (int m = 0; m < 4; ++m) acc[m] = z4;

    const int wcol = (4 * lane) ^ (4 * w);   // swizzled write column
    const int rxor = 4 * cg;                 // swizzle key for reads (row>>2 == cg)

    for (int y = 0; y < YC; ++y) {
        const int buf = y & 1;
        if (y < YC - 1) {                // prefetch next row-block (stays in
            #pragma unroll               //  flight across the raw barrier)
            for (int j = 0; j < 4; ++j)
                nxt[j] = ntld4(fm + ((size_t)(c0 + w * 4 + j) << 16)
                                  + (size_t)(y0 + y + 1) * 256 + 4 * lane);
        }
        // row scan: wave w handles channels w*4..w*4+3, full 256-x per row
        #pragma unroll
        for (int j = 0; j < 4; ++j) {
            const float4 v = cur[j];
            const float local = ((v.x + v.y) + v.z) + v.w;
            float s = local;
            #pragma unroll
            for (int d = 1; d < 64; d <<= 1) {
                float u = __shfl_up(s, d, 64);
                if (lane >= d) s += u;
            }
            const float e = s - local;   // exclusive lane prefix
            float4 p;
            p.x = e   + v.x;
            p.y = p.x + v.y;
            p.z = p.y + v.z;
            p.w = p.z + v.w;
            *(float4*)&tile[buf][w * 4 + j][wcol] = p;
        }
        BAR();
        // col-accumulate + store: per wave, 8 consecutive x * 128B = 1KB
        // contiguous; allocating stores (slice should stay L3-resident).
        const int rowY = y0 + y + 1;
        const size_t rowb = SIDX(cb, rowY, 0);
        #pragma unroll
        for (int m = 0; m < 4; ++m) {
            const int x = x8 + 64 * m;
            const int xs = x ^ rxor;     // swizzled read column (same for all 4 rows)
            float4 a = acc[m];
            a.x += tile[buf][4 * cg + 0][xs];
            a.y += tile[buf][4 * cg + 1][xs];
            a.z += tile[buf][4 * cg + 2][xs];
            a.w += tile[buf][4 * cg + 3][xs];
            acc[m] = a;
            if (rowY < YS)               // row 256 is dead (never read) - elided
                *(float4*)(S + rowb + (size_t)(x + 1) * CB + 4 * cg) = a;
        }
        if (rowY < YS && t < 8)          // x=0 border for this row (128B)
            *(float4*)(S + rowb + 4 * t) = z4;
        #pragma unroll
        for (int j = 0; j < 4; ++j) cur[j] = nxt[j];
        // no second barrier: next y writes the other LDS buffer; y+2's reuse
        // of this buffer is ordered by the y+1 barrier (lgkmcnt(0) there
        // drains this wave's reads before it signals).
    }
}

// ---------------- offset body: fp64 prefix of chunk totals (one slice) -----
// unit u covers gids u*512..u*512+511 of 8*257*32 = 65792 total.
__device__ __forceinline__ void offsetBody(const float* __restrict__ S,
                                           float* __restrict__ OP, int u) {
    const int gid = u * 512 + threadIdx.x;
    if (gid >= 8 * SP * CB) return;
    const int cc = gid & 31;
    const int xr = gid >> 5;           // 0..2055
    const int x  = xr % SP;            // 0..256
    const int cb = xr / SP;            // 0..7
    OP[OPIDX(cb, 0, x) + cc] = 0.0f;
    OP[OPIDX(cb, 1, x) + cc] = 0.0f;
    double run = 0.0;
    #pragma unroll
    for (int j = 0; j < NK - 1; ++j) {
        run += (double)S[SIDX(cb, YC * (j + 1), x) + cc];   // rows 8..248 < YS
        OP[OPIDX(cb, j + 2, x) + cc] = (float)run;
    }
}

// ---------------- gather body: 4 ROIs per 512-thr unit (one group) ---------
__device__ __forceinline__ void gatherBody(const float* __restrict__ S,
                                           const float* __restrict__ OP,
                                           const float* __restrict__ roi,
                                           float* __restrict__ out,
                                           float* __restrict__ maskOut,
                                           int N, int writeMask, int u) {
    const int t = threadIdx.x;
    const int tl = t & 127;               // c-pair within group: channels 2tl,2tl+1
    const int n = u * 4 + (t >> 7);       // ROI index
    const float xmin = roi[4 * n + 0];
    const float ymin = roi[4 * n + 1];
    const float xmax = roi[4 * n + 2];
    const float ymax = roi[4 * n + 3];

    // Replicate np fp32 op order exactly (no fma contraction).
    const float wsv = __fdiv_rn(__fsub_rn(xmax, xmin), 2.0f);
    const float hsv = __fdiv_rn(__fsub_rn(ymax, ymin), 2.0f);
    const float ax1 = __fadd_rn(xmin, wsv);
    const float ay1 = __fadd_rn(ymin, hsv);
    const float lim = (float)(WD - 1);

    int rx[3], ry[3];
    rx[0] = (int)fminf(fmaxf(rintf(xmin), 0.0f), lim);
    rx[1] = (int)fminf(fmaxf(rintf(ax1), 0.0f), lim);
    rx[2] = (int)fminf(fmaxf(rintf(__fadd_rn(ax1, wsv)), 0.0f), lim);
    ry[0] = (int)fminf(fmaxf(rintf(ymin), 0.0f), lim);
    ry[1] = (int)fminf(fmaxf(rintf(ay1), 0.0f), lim);
    ry[2] = (int)fminf(fmaxf(rintf(__fadd_rn(ay1, hsv)), 0.0f), lim);

    const int cbb = tl >> 4;              // cb-block within group 0..7
    const int cc  = (tl & 15) * 2;        // within-block channel 0..30 (even)
    float2 g[3][3];
    #pragma unroll
    for (int j = 0; j < 3; ++j) {
        const int kk = (ry[j] + YC - 1) >> 3;   // chunk-offset row in OP
        #pragma unroll
        for (int i = 0; i < 3; ++i) {
            const float2 l = *(const float2*)(S  + SIDX(cbb, ry[j], rx[i]) + cc);
            const float2 o = *(const float2*)(OP + OPIDX(cbb, kk, rx[i]) + cc);
            g[j][i] = make_float2(l.x + o.x, l.y + o.y);
        }
    }

    float m[4];
    #pragma unroll
    for (int p = 0; p < 4; ++p) {
        const int ix = p & 1, iy = p >> 1;
        const int cw = rx[ix + 1] - rx[ix];
        const int ch = ry[iy + 1] - ry[iy];
        const int maskv = (cw >= 1 && ch >= 1) ? 1 : 0;
        int areai = cw * ch; if (areai < 1) areai = 1;
        const float areaf = (float)areai;
        const float maskf = (float)maskv;
        m[p] = maskf;

        const float2 s11 = g[iy + 1][ix + 1];
        const float2 s01 = g[iy][ix + 1];
        const float2 s10 = g[iy + 1][ix];
        const float2 s00 = g[iy][ix];
        float2 o;  // reference order: ((S11 - S01) - S10) + S00, /area, *mask
        o.x = __fdiv_rn(((s11.x - s01.x) - s10.x) + s00.x, areaf) * maskf;
        o.y = __fdiv_rn(((s11.y - s01.y) - s10.y) + s00.y, areaf) * maskf;
        *(float2*)(out + ((size_t)p * N + n) * CHN + 2 * tl) = o;
    }
    if (writeMask && tl < 4) maskOut[(size_t)tl * N + n] = m[tl];
}

// ---------------- kernels (role-packed fat launches) -----------------------
__global__ __launch_bounds__(512, 4) void scanK(const float* __restrict__ fm,
                                                float* __restrict__ S) {
    __shared__ float tile[2][CB][260];
    scanBody(fm, S, blockIdx.x, tile);
}

// scan(g -> Sdst) || offset(Ssrc -> OPsrc). Roles touch disjoint buffers.
__global__ __launch_bounds__(512, 4) void scanOffK(const float* __restrict__ fm,
                                                   float* __restrict__ Sdst,
                                                   const float* __restrict__ Ssrc,
                                                   float* __restrict__ OPsrc) {
    __shared__ float tile[2][CB][260];
    const int bid = blockIdx.x;
    if (bid < 256) scanBody(fm, Sdst, bid, tile);
    else           offsetBody(Ssrc, OPsrc, bid - 256);
}

// gather(from S,OP) || offset(Sn -> OPn). No LDS: gather keeps full TLP.
__global__ __launch_bounds__(512) void gathOffK(const float* __restrict__ S,
                                                const float* __restrict__ OP,
                                                const float* __restrict__ roi,
                                                float* __restrict__ out,
                                                float* __restrict__ maskOut,
                                                int N, int writeMask,
                                                const float* __restrict__ Sn,
                                                float* __restrict__ OPn) {
    const int bid = blockIdx.x;
    if (bid < OFF_UNITS) offsetBody(Sn, OPn, bid);   // early blocks -> start early
    else gatherBody(S, OP, roi, out, maskOut, N, writeMask, bid - OFF_UNITS);
}

__global__ __launch_bounds__(512) void gathK(const float* __restrict__ S,
                                             const float* __restrict__ OP,
                                             const float* __restrict__ roi,
                                             float* __restrict__ out,
                                             float* __restrict__ maskOut,
                                             int N, int writeMask) {
    gatherBody(S, OP, roi, out, maskOut, N, writeMask, blockIdx.x);
}

// ---------------------------------------------------------------------------
extern "C" void kernel_launch(void* const* d_in, const int* in_sizes, int n_in,
                              void* d_out, int out_size, void* d_ws, size_t ws_size,
                              hipStream_t stream) {
    const float* fm  = (const float*)d_in[0];
    const float* roi = (const float*)d_in[1];
    // d_in[2] = patch_num (always 4 here); pe=2 hardcoded.

    const int N = in_sizes[1] / 4;     // 4096
    const int B = 4 * N;               // 16384

    float* S_A  = (float*)d_ws;
    float* OP_A = S_A + S_SZ;
    float* S_B  = OP_A + OP_SZ;
    float* OP_B = S_B + S_SZ;
    float* out     = (float*)d_out;
    float* maskOut = out + (size_t)B * CHN;

    const float* fm0 = fm;
    const float* fm1 = fm + ((size_t)GCH << 16);

    // L1: scan(g0->A)
    scanK<<<256, 512, 0, stream>>>(fm0, S_A);
    // L2: scan(g1->B) || offset(A)
    scanOffK<<<256 + OFF_UNITS, 512, 0, stream>>>(fm1, S_B, S_A, OP_A);
    // L3: gather(g0:A) || offset(B)
    gathOffK<<<OFF_UNITS + GATH_UNITS, 512, 0, stream>>>(S_A, OP_A, roi,
                                                         out, maskOut, N, 1,
                                                         S_B, OP_B);
    // L4: gather(g1:B)
    gathK<<<GATH_UNITS, 512, 0, stream>>>(S_B, OP_B, roi,
                                          out + GCH, maskOut, N, 0);
}

// Round 10
// 252.587 us; speedup vs baseline: 1.0087x; 1.0087x over previous
//
#include <hip/hip_runtime.h>

// RoiPooling via integral image — CHANNEL-GROUP L3-RESIDENT PIPELINE (round 10).
// G=2 groups of 256 channels, TWO slice sets (A,B), both L3-resident (152.1 MB).
// Launches (stream-serialized; round 9's fat-packing regressed -> plain):
//   L1 scanK : scan(g0->A) + scan(g1->B) as ONE 512-block launch
//              (2 blk/CU, 16 waves/CU — the measured-best scan config,
//               83-86 us in rounds 3-7 vs ~92 as two 1-blk/CU halves)
//   L2 offK  : offset(A) + offset(B)
//   L3 gathK(A, g0) ; L4 gathK(B, g1)   [round-8 split kept: slice-hot reads]
// Gather: float4 per thread (64 thr/ROI x 4 ch) — halves load/store issue
// count vs round 8's float2. Element-wise arithmetic identical everywhere ->
// output bit-identical (absmax exactly 0.001953125).
//
// ws layout (floats):
//   S_A @ 0          8*256*257*32 = 16,842,752
//   OP_A@ 16842752   8*33*257*32  =  2,171,136
//   S_B @ 19013888   16,842,752
//   OP_B@ 35856640    2,171,136      end = 38,027,776 (152.1 MB)

#define CHN 512
#define WD  256
#define SP  257               // x-extent 0..256 (col 256 written, unread)
#define YS  256               // y-extent 0..255 (row 256 dead -> dropped)
#define YC  8                 // rows per y-chunk
#define NK  32                // number of y-chunks
#define CB  32                // channels per cb-block / innermost S dim
#define GCH 256               // channels per group

#define SIDX(cb, y, x)   ((((size_t)(cb) * YS + (y)) * SP + (x)) * CB)
#define OPIDX(cb, kk, x) ((((size_t)(cb) * 33 + (kk)) * SP + (x)) * CB)

#define S_SZ  ((size_t)8 * YS * SP * CB)   // 16,842,752 floats
#define OP_SZ ((size_t)8 * 33 * SP * CB)   //  2,171,136 floats

#define OFF_UNITS 129          // ceil(8*257*32 / 512) per slice

typedef float f32x4v __attribute__((ext_vector_type(4)));

__device__ __forceinline__ float4 ntld4(const float* p) {   // streaming load
    f32x4v u = __builtin_nontemporal_load((const f32x4v*)p);
    return make_float4(u.x, u.y, u.z, u.w);
}

// Raw barrier: LDS-drain only, NO vmcnt(0) (keeps prefetch loads + S stores
// in flight across y-steps). lgkmcnt(0) drains this wave's ds_writes
// (producer visibility) and ds_reads (WAR safety for y+2 buffer reuse).
// Trailing empty asm stops LLVM hoisting post-barrier LDS reads.
#define BAR() do { asm volatile("s_waitcnt lgkmcnt(0)" ::: "memory"); \
                   __builtin_amdgcn_s_barrier(); \
                   asm volatile("" ::: "memory"); } while (0)

// ---------------- scan body: fm-group -> S-slice (chunk-local integral) ----
// One 512-thr block = tile 32c x 256x x 8y. bid in [0,256): cb=bid&7, k=bid>>3.
// LDS XOR swizzle col ^= 4*(row>>2): unswizzled store-phase reads were a
// deterministic 4-way bank conflict; swizzled: 0 (verified round 3).
__device__ __forceinline__ void scanBody(const float* __restrict__ fm,
                                         float* __restrict__ S,
                                         int bid, float tile[2][CB][260]) {
    const int t = threadIdx.x, lane = t & 63, w = t >> 6;   // w = wave 0..7
    const int cb = bid & 7;              // cb-block within group
    const int c0 = cb * CB;              // channel offset within group
    const int k  = bid >> 3;             // y-chunk 0..31
    const int y0 = k * YC;

    const int cg = t & 7;                // store: 4-channel group (8 groups = 32 ch)
    const int x8 = t >> 3;               // store: x mod 64
    const float4 z4 = make_float4(0.f, 0.f, 0.f, 0.f);

    if (k == 0) {                        // y=0 border row, x=0..255
        #pragma unroll
        for (int it = 0; it < 4; ++it) {
            const int lin = it * 512 + t;
            const int cgg = lin & 7, x = lin >> 3;
            *(float4*)(S + SIDX(cb, 0, x) + 4 * cgg) = z4;
        }
    }

    float4 cur[4], nxt[4];
    #pragma unroll
    for (int j = 0; j < 4; ++j)
        cur[j] = ntld4(fm + ((size_t)(c0 + w * 4 + j) << 16)
                          + (size_t)y0 * 256 + 4 * lane);

    float4 acc[4];
    #pragma unroll
    for (int m = 0; m < 4; ++m) acc[m] = z4;

    const int wcol = (4 * lane) ^ (4 * w);   // swizzled write column
    const int rxor = 4 * cg;                 // swizzle key for reads (row>>2 == cg)

    for (int y = 0; y < YC; ++y) {
        const int buf = y & 1;
        if (y < YC - 1) {                // prefetch next row-block (stays in
            #pragma unroll               //  flight across the raw barrier)
            for (int j = 0; j < 4; ++j)
                nxt[j] = ntld4(fm + ((size_t)(c0 + w * 4 + j) << 16)
                                  + (size_t)(y0 + y + 1) * 256 + 4 * lane);
        }
        // row scan: wave w handles channels w*4..w*4+3, full 256-x per row
        #pragma unroll
        for (int j = 0; j < 4; ++j) {
            const float4 v = cur[j];
            const float local = ((v.x + v.y) + v.z) + v.w;
            float s = local;
            #pragma unroll
            for (int d = 1; d < 64; d <<= 1) {
                float u = __shfl_up(s, d, 64);
                if (lane >= d) s += u;
            }
            const float e = s - local;   // exclusive lane prefix
            float4 p;
            p.x = e   + v.x;
            p.y = p.x + v.y;
            p.z = p.y + v.z;
            p.w = p.z + v.w;
            *(float4*)&tile[buf][w * 4 + j][wcol] = p;
        }
        BAR();
        // col-accumulate + store: per wave, 8 consecutive x * 128B = 1KB
        // contiguous; allocating stores (slice should stay L3-resident).
        const int rowY = y0 + y + 1;
        const size_t rowb = SIDX(cb, rowY, 0);
        #pragma unroll
        for (int m = 0; m < 4; ++m) {
            const int x = x8 + 64 * m;
            const int xs = x ^ rxor;     // swizzled read column (same for all 4 rows)
            float4 a = acc[m];
            a.x += tile[buf][4 * cg + 0][xs];
            a.y += tile[buf][4 * cg + 1][xs];
            a.z += tile[buf][4 * cg + 2][xs];
            a.w += tile[buf][4 * cg + 3][xs];
            acc[m] = a;
            if (rowY < YS)               // row 256 is dead (never read) - elided
                *(float4*)(S + rowb + (size_t)(x + 1) * CB + 4 * cg) = a;
        }
        if (rowY < YS && t < 8)          // x=0 border for this row (128B)
            *(float4*)(S + rowb + 4 * t) = z4;
        #pragma unroll
        for (int j = 0; j < 4; ++j) cur[j] = nxt[j];
        // no second barrier: next y writes the other LDS buffer; y+2's reuse
        // of this buffer is ordered by the y+1 barrier (lgkmcnt(0) there
        // drains this wave's reads before it signals).
    }
}

// ---------------- merged scan kernel: 512 blocks = g0->A, g1->B ------------
__global__ __launch_bounds__(512, 4) void scanK(const float* __restrict__ fm,
                                                float* __restrict__ S_A,
                                                float* __restrict__ S_B) {
    __shared__ float tile[2][CB][260];
    const int bid = blockIdx.x;
    const int g = bid >> 8;              // group 0/1
    const float* fm_g = fm + ((size_t)(g * GCH) << 16);
    float* Sg = g ? S_B : S_A;
    scanBody(fm_g, Sg, bid & 255, tile);
}

// ---------------- offset: fp64 prefix of chunk totals, both slices ---------
__global__ __launch_bounds__(512) void offK(const float* __restrict__ S_A,
                                            float* __restrict__ OP_A,
                                            const float* __restrict__ S_B,
                                            float* __restrict__ OP_B) {
    int u = blockIdx.x;
    const float* S = (u < OFF_UNITS) ? S_A : S_B;
    float* OP      = (u < OFF_UNITS) ? OP_A : OP_B;
    if (u >= OFF_UNITS) u -= OFF_UNITS;
    const int gid = u * 512 + threadIdx.x;
    if (gid >= 8 * SP * CB) return;
    const int cc = gid & 31;
    const int xr = gid >> 5;           // 0..2055
    const int x  = xr % SP;            // 0..256
    const int cb = xr / SP;            // 0..7
    OP[OPIDX(cb, 0, x) + cc] = 0.0f;
    OP[OPIDX(cb, 1, x) + cc] = 0.0f;
    double run = 0.0;
    #pragma unroll
    for (int j = 0; j < NK - 1; ++j) {
        run += (double)S[SIDX(cb, YC * (j + 1), x) + cc];   // rows 8..248 < YS
        OP[OPIDX(cb, j + 2, x) + cc] = (float)run;
    }
}

// ---------------- gather: 4 ROIs per 256-thr block, float4 channels --------
// 64 threads/ROI, each owns 4 consecutive channels (cbb*32 + cc..cc+3).
// Per-channel arithmetic identical to the float2 version -> bit-identical.
__global__ __launch_bounds__(256) void gathK(const float* __restrict__ S,
                                             const float* __restrict__ OP,
                                             const float* __restrict__ roi,
                                             float* __restrict__ out,
                                             float* __restrict__ maskOut,
                                             int N, int writeMask) {
    const int t = threadIdx.x;
    const int tl = t & 63;                // c-quad within group
    const int n = blockIdx.x * 4 + (t >> 6);
    const float xmin = roi[4 * n + 0];
    const float ymin = roi[4 * n + 1];
    const float xmax = roi[4 * n + 2];
    const float ymax = roi[4 * n + 3];

    // Replicate np fp32 op order exactly (no fma contraction).
    const float wsv = __fdiv_rn(__fsub_rn(xmax, xmin), 2.0f);
    const float hsv = __fdiv_rn(__fsub_rn(ymax, ymin), 2.0f);
    const float ax1 = __fadd_rn(xmin, wsv);
    const float ay1 = __fadd_rn(ymin, hsv);
    const float lim = (float)(WD - 1);

    int rx[3], ry[3];
    rx[0] = (int)fminf(fmaxf(rintf(xmin), 0.0f), lim);
    rx[1] = (int)fminf(fmaxf(rintf(ax1), 0.0f), lim);
    rx[2] = (int)fminf(fmaxf(rintf(__fadd_rn(ax1, wsv)), 0.0f), lim);
    ry[0] = (int)fminf(fmaxf(rintf(ymin), 0.0f), lim);
    ry[1] = (int)fminf(fmaxf(rintf(ay1), 0.0f), lim);
    ry[2] = (int)fminf(fmaxf(rintf(__fadd_rn(ay1, hsv)), 0.0f), lim);

    const int cbb = tl >> 3;              // cb-block within group 0..7
    const int cc  = (tl & 7) * 4;         // within-block channel 0,4,..,28
    float4 g[3][3];
    #pragma unroll
    for (int j = 0; j < 3; ++j) {
        const int kk = (ry[j] + YC - 1) >> 3;   // chunk-offset row in OP
        #pragma unroll
        for (int i = 0; i < 3; ++i) {
            const float4 l = *(const float4*)(S  + SIDX(cbb, ry[j], rx[i]) + cc);
            const float4 o = *(const float4*)(OP + OPIDX(cbb, kk, rx[i]) + cc);
            g[j][i] = make_float4(l.x + o.x, l.y + o.y, l.z + o.z, l.w + o.w);
        }
    }

    float m[4];
    #pragma unroll
    for (int p = 0; p < 4; ++p) {
        const int ix = p & 1, iy = p >> 1;
        const int cw = rx[ix + 1] - rx[ix];
        const int ch = ry[iy + 1] - ry[iy];
        const int maskv = (cw >= 1 && ch >= 1) ? 1 : 0;
        int areai = cw * ch; if (areai < 1) areai = 1;
        const float areaf = (float)areai;
        const float maskf = (float)maskv;
        m[p] = maskf;

        const float4 s11 = g[iy + 1][ix + 1];
        const float4 s01 = g[iy][ix + 1];
        const float4 s10 = g[iy + 1][ix];
        const float4 s00 = g[iy][ix];
        float4 o;  // reference order: ((S11 - S01) - S10) + S00, /area, *mask
        o.x = __fdiv_rn(((s11.x - s01.x) - s10.x) + s00.x, areaf) * maskf;
        o.y = __fdiv_rn(((s11.y - s01.y) - s10.y) + s00.y, areaf) * maskf;
        o.z = __fdiv_rn(((s11.z - s01.z) - s10.z) + s00.z, areaf) * maskf;
        o.w = __fdiv_rn(((s11.w - s01.w) - s10.w) + s00.w, areaf) * maskf;
        *(float4*)(out + ((size_t)p * N + n) * CHN + 4 * tl) = o;
    }
    if (writeMask && tl < 4) maskOut[(size_t)tl * N + n] = m[tl];
}

// ---------------------------------------------------------------------------
extern "C" void kernel_launch(void* const* d_in, const int* in_sizes, int n_in,
                              void* d_out, int out_size, void* d_ws, size_t ws_size,
                              hipStream_t stream) {
    const float* fm  = (const float*)d_in[0];
    const float* roi = (const float*)d_in[1];
    // d_in[2] = patch_num (always 4 here); pe=2 hardcoded.

    const int N = in_sizes[1] / 4;     // 4096
    const int B = 4 * N;               // 16384

    float* S_A  = (float*)d_ws;
    float* OP_A = S_A + S_SZ;
    float* S_B  = OP_A + OP_SZ;
    float* OP_B = S_B + S_SZ;
    float* out     = (float*)d_out;
    float* maskOut = out + (size_t)B * CHN;

    // L1: both group scans, 512 blocks (2/CU, 16 waves/CU)
    scanK<<<512, 512, 0, stream>>>(fm, S_A, S_B);
    // L2: both offsets
    offK<<<2 * OFF_UNITS, 512, 0, stream>>>(S_A, OP_A, S_B, OP_B);
    // L3/L4: gathers per group (slice-hot reads)
    gathK<<<N / 4, 256, 0, stream>>>(S_A, OP_A, roi, out, maskOut, N, 1);
    gathK<<<N / 4, 256, 0, stream>>>(S_B, OP_B, roi, out + GCH, maskOut, N, 0);
}

// Round 11
// 252.324 us; speedup vs baseline: 1.0098x; 1.0010x over previous
//
#include <hip/hip_runtime.h>

// RoiPooling via integral image — CHANNEL-GROUP L3-RESIDENT PIPELINE (round 11).
// G=2 groups of 256 channels, TWO slice sets (A,B), both L3-resident (152.1 MB).
// Launches (stream-serialized):
//   L1 scanK : scan(g0->A) + scan(g1->B), 512 blocks (2/CU, 16 waves/CU)
//   L2 offK  : offset(A) + offset(B)
//   L3 gathK : gather(A,g0) + gather(B,g1) MERGED, 2048 blocks
// Round-11 lever: the two gathers (inferred ~150 us combined, the dominant
// term; each under the 83-us fill so never in top-5) are independent after
// offK — merging doubles in-flight load streams for a phase whose traffic
// (~75 MB of scattered 128B segments per group, L3-resident) says ~20 us,
// i.e. latency-bound, not BW-bound. All compute bodies byte-identical ->
// output bit-identical (absmax exactly 0.001953125).
//
// ws layout (floats):
//   S_A @ 0          8*256*257*32 = 16,842,752
//   OP_A@ 16842752   8*33*257*32  =  2,171,136
//   S_B @ 19013888   16,842,752
//   OP_B@ 35856640    2,171,136      end = 38,027,776 (152.1 MB)

#define CHN 512
#define WD  256
#define SP  257               // x-extent 0..256 (col 256 written, unread)
#define YS  256               // y-extent 0..255 (row 256 dead -> dropped)
#define YC  8                 // rows per y-chunk
#define NK  32                // number of y-chunks
#define CB  32                // channels per cb-block / innermost S dim
#define GCH 256               // channels per group

#define SIDX(cb, y, x)   ((((size_t)(cb) * YS + (y)) * SP + (x)) * CB)
#define OPIDX(cb, kk, x) ((((size_t)(cb) * 33 + (kk)) * SP + (x)) * CB)

#define S_SZ  ((size_t)8 * YS * SP * CB)   // 16,842,752 floats
#define OP_SZ ((size_t)8 * 33 * SP * CB)   //  2,171,136 floats

#define OFF_UNITS 129          // ceil(8*257*32 / 512) per slice

typedef float f32x4v __attribute__((ext_vector_type(4)));

__device__ __forceinline__ float4 ntld4(const float* p) {   // streaming load
    f32x4v u = __builtin_nontemporal_load((const f32x4v*)p);
    return make_float4(u.x, u.y, u.z, u.w);
}

// Raw barrier: LDS-drain only, NO vmcnt(0) (keeps prefetch loads + S stores
// in flight across y-steps). lgkmcnt(0) drains this wave's ds_writes
// (producer visibility) and ds_reads (WAR safety for y+2 buffer reuse).
// Trailing empty asm stops LLVM hoisting post-barrier LDS reads.
#define BAR() do { asm volatile("s_waitcnt lgkmcnt(0)" ::: "memory"); \
                   __builtin_amdgcn_s_barrier(); \
                   asm volatile("" ::: "memory"); } while (0)

// ---------------- scan body: fm-group -> S-slice (chunk-local integral) ----
// One 512-thr block = tile 32c x 256x x 8y. bid in [0,256): cb=bid&7, k=bid>>3.
// LDS XOR swizzle col ^= 4*(row>>2): unswizzled store-phase reads were a
// deterministic 4-way bank conflict; swizzled: 0 (verified round 3).
__device__ __forceinline__ void scanBody(const float* __restrict__ fm,
                                         float* __restrict__ S,
                                         int bid, float tile[2][CB][260]) {
    const int t = threadIdx.x, lane = t & 63, w = t >> 6;   // w = wave 0..7
    const int cb = bid & 7;              // cb-block within group
    const int c0 = cb * CB;              // channel offset within group
    const int k  = bid >> 3;             // y-chunk 0..31
    const int y0 = k * YC;

    const int cg = t & 7;                // store: 4-channel group (8 groups = 32 ch)
    const int x8 = t >> 3;               // store: x mod 64
    const float4 z4 = make_float4(0.f, 0.f, 0.f, 0.f);

    if (k == 0) {                        // y=0 border row, x=0..255
        #pragma unroll
        for (int it = 0; it < 4; ++it) {
            const int lin = it * 512 + t;
            const int cgg = lin & 7, x = lin >> 3;
            *(float4*)(S + SIDX(cb, 0, x) + 4 * cgg) = z4;
        }
    }

    float4 cur[4], nxt[4];
    #pragma unroll
    for (int j = 0; j < 4; ++j)
        cur[j] = ntld4(fm + ((size_t)(c0 + w * 4 + j) << 16)
                          + (size_t)y0 * 256 + 4 * lane);

    float4 acc[4];
    #pragma unroll
    for (int m = 0; m < 4; ++m) acc[m] = z4;

    const int wcol = (4 * lane) ^ (4 * w);   // swizzled write column
    const int rxor = 4 * cg;                 // swizzle key for reads (row>>2 == cg)

    for (int y = 0; y < YC; ++y) {
        const int buf = y & 1;
        if (y < YC - 1) {                // prefetch next row-block (stays in
            #pragma unroll               //  flight across the raw barrier)
            for (int j = 0; j < 4; ++j)
                nxt[j] = ntld4(fm + ((size_t)(c0 + w * 4 + j) << 16)
                                  + (size_t)(y0 + y + 1) * 256 + 4 * lane);
        }
        // row scan: wave w handles channels w*4..w*4+3, full 256-x per row
        #pragma unroll
        for (int j = 0; j < 4; ++j) {
            const float4 v = cur[j];
            const float local = ((v.x + v.y) + v.z) + v.w;
            float s = local;
            #pragma unroll
            for (int d = 1; d < 64; d <<= 1) {
                float u = __shfl_up(s, d, 64);
                if (lane >= d) s += u;
            }
            const float e = s - local;   // exclusive lane prefix
            float4 p;
            p.x = e   + v.x;
            p.y = p.x + v.y;
            p.z = p.y + v.z;
            p.w = p.z + v.w;
            *(float4*)&tile[buf][w * 4 + j][wcol] = p;
        }
        BAR();
        // col-accumulate + store: per wave, 8 consecutive x * 128B = 1KB
        // contiguous; allocating stores (slice should stay L3-resident).
        const int rowY = y0 + y + 1;
        const size_t rowb = SIDX(cb, rowY, 0);
        #pragma unroll
        for (int m = 0; m < 4; ++m) {
            const int x = x8 + 64 * m;
            const int xs = x ^ rxor;     // swizzled read column (same for all 4 rows)
            float4 a = acc[m];
            a.x += tile[buf][4 * cg + 0][xs];
            a.y += tile[buf][4 * cg + 1][xs];
            a.z += tile[buf][4 * cg + 2][xs];
            a.w += tile[buf][4 * cg + 3][xs];
            acc[m] = a;
            if (rowY < YS)               // row 256 is dead (never read) - elided
                *(float4*)(S + rowb + (size_t)(x + 1) * CB + 4 * cg) = a;
        }
        if (rowY < YS && t < 8)          // x=0 border for this row (128B)
            *(float4*)(S + rowb + 4 * t) = z4;
        #pragma unroll
        for (int j = 0; j < 4; ++j) cur[j] = nxt[j];
        // no second barrier: next y writes the other LDS buffer; y+2's reuse
        // of this buffer is ordered by the y+1 barrier (lgkmcnt(0) there
        // drains this wave's reads before it signals).
    }
}

// ---------------- merged scan kernel: 512 blocks = g0->A, g1->B ------------
__global__ __launch_bounds__(512, 4) void scanK(const float* __restrict__ fm,
                                                float* __restrict__ S_A,
                                                float* __restrict__ S_B) {
    __shared__ float tile[2][CB][260];
    const int bid = blockIdx.x;
    const int g = bid >> 8;              // group 0/1
    const float* fm_g = fm + ((size_t)(g * GCH) << 16);
    float* Sg = g ? S_B : S_A;
    scanBody(fm_g, Sg, bid & 255, tile);
}

// ---------------- offset: fp64 prefix of chunk totals, both slices ---------
__global__ __launch_bounds__(512) void offK(const float* __restrict__ S_A,
                                            float* __restrict__ OP_A,
                                            const float* __restrict__ S_B,
                                            float* __restrict__ OP_B) {
    int u = blockIdx.x;
    const float* S = (u < OFF_UNITS) ? S_A : S_B;
    float* OP      = (u < OFF_UNITS) ? OP_A : OP_B;
    if (u >= OFF_UNITS) u -= OFF_UNITS;
    const int gid = u * 512 + threadIdx.x;
    if (gid >= 8 * SP * CB) return;
    const int cc = gid & 31;
    const int xr = gid >> 5;           // 0..2055
    const int x  = xr % SP;            // 0..256
    const int cb = xr / SP;            // 0..7
    OP[OPIDX(cb, 0, x) + cc] = 0.0f;
    OP[OPIDX(cb, 1, x) + cc] = 0.0f;
    double run = 0.0;
    #pragma unroll
    for (int j = 0; j < NK - 1; ++j) {
        run += (double)S[SIDX(cb, YC * (j + 1), x) + cc];   // rows 8..248 < YS
        OP[OPIDX(cb, j + 2, x) + cc] = (float)run;
    }
}

// ---------------- merged gather: 2048 blocks = 1024 per group --------------
// 4 ROIs per 256-thr block; 64 thr/ROI, each owns 4 consecutive channels.
// Per-channel arithmetic identical to round 8/10 -> bit-identical output.
__global__ __launch_bounds__(256) void gathK(const float* __restrict__ S_A,
                                             const float* __restrict__ OP_A,
                                             const float* __restrict__ S_B,
                                             const float* __restrict__ OP_B,
                                             const float* __restrict__ roi,
                                             float* __restrict__ out,
                                             float* __restrict__ maskOut,
                                             int N) {
    const int bid = blockIdx.x;
    const int g = bid >> 10;              // group 0/1 (1024 blocks each)
    const int u = bid & 1023;
    const float* S  = g ? S_B  : S_A;
    const float* OP = g ? OP_B : OP_A;
    float* outg = out + g * GCH;

    const int t = threadIdx.x;
    const int tl = t & 63;                // c-quad within group
    const int n = u * 4 + (t >> 6);
    const float xmin = roi[4 * n + 0];
    const float ymin = roi[4 * n + 1];
    const float xmax = roi[4 * n + 2];
    const float ymax = roi[4 * n + 3];

    // Replicate np fp32 op order exactly (no fma contraction).
    const float wsv = __fdiv_rn(__fsub_rn(xmax, xmin), 2.0f);
    const float hsv = __fdiv_rn(__fsub_rn(ymax, ymin), 2.0f);
    const float ax1 = __fadd_rn(xmin, wsv);
    const float ay1 = __fadd_rn(ymin, hsv);
    const float lim = (float)(WD - 1);

    int rx[3], ry[3];
    rx[0] = (int)fminf(fmaxf(rintf(xmin), 0.0f), lim);
    rx[1] = (int)fminf(fmaxf(rintf(ax1), 0.0f), lim);
    rx[2] = (int)fminf(fmaxf(rintf(__fadd_rn(ax1, wsv)), 0.0f), lim);
    ry[0] = (int)fminf(fmaxf(rintf(ymin), 0.0f), lim);
    ry[1] = (int)fminf(fmaxf(rintf(ay1), 0.0f), lim);
    ry[2] = (int)fminf(fmaxf(rintf(__fadd_rn(ay1, hsv)), 0.0f), lim);

    const int cbb = tl >> 3;              // cb-block within group 0..7
    const int cc  = (tl & 7) * 4;         // within-block channel 0,4,..,28
    float4 gv[3][3];
    #pragma unroll
    for (int j = 0; j < 3; ++j) {
        const int kk = (ry[j] + YC - 1) >> 3;   // chunk-offset row in OP
        #pragma unroll
        for (int i = 0; i < 3; ++i) {
            const float4 l = *(const float4*)(S  + SIDX(cbb, ry[j], rx[i]) + cc);
            const float4 o = *(const float4*)(OP + OPIDX(cbb, kk, rx[i]) + cc);
            gv[j][i] = make_float4(l.x + o.x, l.y + o.y, l.z + o.z, l.w + o.w);
        }
    }

    float m[4];
    #pragma unroll
    for (int p = 0; p < 4; ++p) {
        const int ix = p & 1, iy = p >> 1;
        const int cw = rx[ix + 1] - rx[ix];
        const int ch = ry[iy + 1] - ry[iy];
        const int maskv = (cw >= 1 && ch >= 1) ? 1 : 0;
        int areai = cw * ch; if (areai < 1) areai = 1;
        const float areaf = (float)areai;
        const float maskf = (float)maskv;
        m[p] = maskf;

        const float4 s11 = gv[iy + 1][ix + 1];
        const float4 s01 = gv[iy][ix + 1];
        const float4 s10 = gv[iy + 1][ix];
        const float4 s00 = gv[iy][ix];
        float4 o;  // reference order: ((S11 - S01) - S10) + S00, /area, *mask
        o.x = __fdiv_rn(((s11.x - s01.x) - s10.x) + s00.x, areaf) * maskf;
        o.y = __fdiv_rn(((s11.y - s01.y) - s10.y) + s00.y, areaf) * maskf;
        o.z = __fdiv_rn(((s11.z - s01.z) - s10.z) + s00.z, areaf) * maskf;
        o.w = __fdiv_rn(((s11.w - s01.w) - s10.w) + s00.w, areaf) * maskf;
        *(float4*)(outg + ((size_t)p * N + n) * CHN + 4 * tl) = o;
    }
    if (g == 0 && tl < 4) maskOut[(size_t)tl * N + n] = m[tl];
}

// ---------------------------------------------------------------------------
extern "C" void kernel_launch(void* const* d_in, const int* in_sizes, int n_in,
                              void* d_out, int out_size, void* d_ws, size_t ws_size,
                              hipStream_t stream) {
    const float* fm  = (const float*)d_in[0];
    const float* roi = (const float*)d_in[1];
    // d_in[2] = patch_num (always 4 here); pe=2 hardcoded.

    const int N = in_sizes[1] / 4;     // 4096
    const int B = 4 * N;               // 16384

    float* S_A  = (float*)d_ws;
    float* OP_A = S_A + S_SZ;
    float* S_B  = OP_A + OP_SZ;
    float* OP_B = S_B + S_SZ;
    float* out     = (float*)d_out;
    float* maskOut = out + (size_t)B * CHN;

    // L1: both group scans, 512 blocks (2/CU, 16 waves/CU)
    scanK<<<512, 512, 0, stream>>>(fm, S_A, S_B);
    // L2: both offsets
    offK<<<2 * OFF_UNITS, 512, 0, stream>>>(S_A, OP_A, S_B, OP_B);
    // L3: both gathers merged (independent after offK; 2x load streams)
    gathK<<<2048, 256, 0, stream>>>(S_A, OP_A, S_B, OP_B, roi,
                                    out, maskOut, N);
}